// Round 12
// baseline (344.529 us; speedup 1.0000x reference)
//
#include <hip/hip_runtime.h>

#define N_NODES 100000
#define N_EDGES 1600000
#define DIM 128
#define BN_EPS 1e-5f
#define BM 64       // GEMM rows per block
#define BSHIFT 9    // bucket = dst >> 9  (512 nodes/bucket)
#define BN 512      // nodes per bucket
#define NB 196      // ceil(N_NODES / BN)
#define CAP_S 9216  // staged edges per bucket (real; mean 8192, sigma ~90, +11s)
#define CAP_C 10048 // col entries per bucket (padded; mean ~8960, sigma ~93, +11s)
#define CHUNK 4096  // edges per phase-A block
#define NSL 8       // column slices (16 cols = 32 B each); slice s -> XCD s

typedef _Float16 f16;
typedef _Float16 f16x4 __attribute__((ext_vector_type(4)));
typedef _Float16 f16x8 __attribute__((ext_vector_type(8)));
typedef float f32x4 __attribute__((ext_vector_type(4)));

union h44 { f16x4 h[2]; f16x8 v; };

// ---------------- CSR build (bucketed, padded-to-4 adjacency) ----------------

__global__ void k_bzero(int* __restrict__ bcnt) {
  int t = threadIdx.x;
  if (t < NB) bcnt[t] = 0;
}

__global__ __launch_bounds__(256) void k_binA(const int* __restrict__ src,
                                              const int* __restrict__ dst,
                                              int* __restrict__ bcnt,
                                              int2* __restrict__ stage) {
  __shared__ int hist[NB];
  __shared__ int lofs[NB];
  __shared__ int lbase[NB];
  __shared__ int lcur[NB];
  __shared__ int scanbuf[256];
  __shared__ int2 buf[CHUNK];  // 32 KB
  int t = threadIdx.x;
  for (int i = t; i < NB; i += 256) { hist[i] = 0; lcur[i] = 0; }
  __syncthreads();
  int e0 = blockIdx.x * CHUNK;
  int en = min(CHUNK, N_EDGES - e0);
  for (int i = t; i < en; i += 256) {
    unsigned d = (unsigned)dst[e0 + i];
    unsigned s = (unsigned)src[e0 + i];
    if (d < N_NODES && s < N_NODES) atomicAdd(&hist[d >> BSHIFT], 1);
  }
  __syncthreads();
  scanbuf[t] = (t < NB) ? hist[t] : 0;
  __syncthreads();
  for (int off = 1; off < 256; off <<= 1) {
    int x = (t >= off) ? scanbuf[t - off] : 0;
    __syncthreads();
    scanbuf[t] += x;
    __syncthreads();
  }
  if (t < NB) {
    lofs[t] = scanbuf[t] - hist[t];
    lbase[t] = atomicAdd(&bcnt[t], hist[t]);
  }
  __syncthreads();
  for (int i = t; i < en; i += 256) {
    int d = dst[e0 + i], s = src[e0 + i];
    if ((unsigned)d < N_NODES && (unsigned)s < N_NODES) {
      int b = d >> BSHIFT;
      int r = atomicAdd(&lcur[b], 1);
      buf[lofs[b] + r] = make_int2(d, s);
    }
  }
  __syncthreads();
  int tot = lofs[NB - 1] + hist[NB - 1];
  for (int i = t; i < tot; i += 256) {
    int2 p = buf[i];
    int b = p.x >> BSHIFT;
    int goff = lbase[b] + (i - lofs[b]);
    if (goff < CAP_S) stage[(size_t)b * CAP_S + goff] = p;
  }
}

// Phase B: per-bucket CSR in LDS, adjacency padded to x4 with zero-row index N_NODES.
__global__ __launch_bounds__(512) void k_binB(const int2* __restrict__ stage,
                                              const int* __restrict__ bcnt,
                                              int* __restrict__ rowpack,
                                              int* __restrict__ col) {
  __shared__ int cnt[BN];
  __shared__ int offs[BN];
  __shared__ int lcur[BN];
  __shared__ int sb[BN];
  __shared__ int mp_s;
  __shared__ int colbuf[CAP_C];  // 40 KB
  int b = blockIdx.x, t = threadIdx.x;
  int base = b << BSHIFT;
  int nn = min(BN, N_NODES - base);
  int m = min(bcnt[b], CAP_S);
  const int2* seg = stage + (size_t)b * CAP_S;
  cnt[t] = 0; lcur[t] = 0;
  __syncthreads();
  for (int i = t; i < m; i += 512) atomicAdd(&cnt[seg[i].x - base], 1);
  __syncthreads();
  int pcnt = (cnt[t] + 3) & ~3;
  sb[t] = pcnt;
  __syncthreads();
  for (int off = 1; off < 512; off <<= 1) {
    int x = (t >= off) ? sb[t - off] : 0;
    __syncthreads();
    sb[t] += x;
    __syncthreads();
  }
  offs[t] = sb[t] - pcnt;
  if (t == 511) mp_s = sb[511];
  __syncthreads();
  for (int i = t; i < m; i += 512) {
    int2 p = seg[i];
    int dl = p.x - base;
    int r = atomicAdd(&lcur[dl], 1);
    int o = offs[dl] + r;
    if (o < CAP_C) colbuf[o] = p.y;
  }
  __syncthreads();
  {
    int o = offs[t], c = cnt[t], pc = (c + 3) & ~3;
    for (int k = c; k < pc; k++)
      if (o + k < CAP_C) colbuf[o + k] = N_NODES;
  }
  __syncthreads();
  if (t < nn) {
    int o = offs[t], c = cnt[t];
    if (o + ((c + 3) & ~3) > CAP_C) { o = 0; c = 0; }
    rowpack[base + t] = (o << 14) | c;
  }
  int mp = min(mp_s, CAP_C);
  for (int i = t; i < mp; i += 512) col[b * CAP_C + i] = colbuf[i];
}

// ---------------- precompute ----------------

// x fp32 row-major -> h16 slice-major [NSL][N][2 x f16x8], via LDS transpose.
__global__ __launch_bounds__(256) void k_xslice(const float* __restrict__ x,
                                                f16* __restrict__ h16) {
  __shared__ f16x4 lds[128 * 32];  // 32 KB: [row][u] u = col/4, xor-swizzled
  int t = threadIdx.x;
  int node0 = blockIdx.x * 128;
  const float4* xf4 = (const float4*)x;
  #pragma unroll
  for (int i = 0; i < 16; i++) {
    int q = t + i * 256;          // 4096 float4 = 128 rows x 32
    int row = q >> 5, u = q & 31;
    int gr = node0 + row; if (gr >= N_NODES) gr = N_NODES - 1;
    float4 v = xf4[(size_t)gr * 32 + u];
    f16x4 o = {(f16)v.x, (f16)v.y, (f16)v.z, (f16)v.w};
    lds[row * 32 + (u ^ ((row & 7) << 2))] = o;
  }
  __syncthreads();
  f16x8* hg = (f16x8*)h16;
  #pragma unroll
  for (int i = 0; i < 8; i++) {
    int q = t + i * 256;          // 2048 f16x8 = 8 slices x 128 (row,half)
    int sl = q >> 8, rem = q & 255;
    int row = rem >> 1, half = rem & 1;
    int gr = node0 + row;
    if (gr < N_NODES) {
      int u0 = (sl * 4 + half * 2) ^ ((row & 7) << 2);
      h44 c; c.h[0] = lds[row * 32 + u0]; c.h[1] = lds[row * 32 + u0 + 1];
      hg[(size_t)(sl * N_NODES + gr) * 2 + half] = c.v;
    }
  }
}

// W[k][c] fp32 -> Wt[c][k] fp16; block 0 also zeroes hws pad row N (all slices)
__global__ void k_wprep(const float* __restrict__ W, f16* __restrict__ Wt,
                        f16* __restrict__ hws) {
  int t = blockIdx.x * blockDim.x + threadIdx.x;
  if (t < DIM * DIM) {
    int c = t >> 7, k = t & 127;
    Wt[t] = (f16)W[k * DIM + c];
  }
  if (blockIdx.x == 0 && threadIdx.x < 16) {
    int s = threadIdx.x >> 1, half = threadIdx.x & 1;
    f16x8 z = {};
    ((f16x8*)hws)[(size_t)(s * (N_NODES + 1) + N_NODES) * 2 + half] = z;
  }
}

__global__ void k_bnprep(const float* __restrict__ b, const float* __restrict__ gamma,
                         const float* __restrict__ beta, const float* __restrict__ mean,
                         const float* __restrict__ var, float* __restrict__ scsh) {
  int t = threadIdx.x;  // 384 = 3 layers x 128 cols
  if (t < 384) {
    int l = t >> 7, c = t & 127, i = l * DIM + c;
    float sc = gamma[i] * rsqrtf(var[i] + BN_EPS);
    scsh[l * 256 + c] = sc;
    scsh[l * 256 + 128 + c] = sc * (b[i] - mean[i]) + beta[i];
  }
}

// ---------------- MFMA GEMM: reads h16 slice-major, writes hws slice-major ----------------

__global__ __launch_bounds__(256) void k_gemm16(const f16* __restrict__ H16,
                                                const f16* __restrict__ Wt16,
                                                const int* __restrict__ rowpack,
                                                f16* __restrict__ HWS16) {
  __shared__ f16x8 Hs[BM * 16];    // 16 KB
  __shared__ f16x8 WtS[DIM * 16];  // 32 KB
  int t = threadIdx.x;
  int row0 = blockIdx.x * BM;

  const f16x8* Hg = (const f16x8*)H16;
  #pragma unroll
  for (int i = 0; i < 4; i++) {    // 1024 = 8 slices x (64 rows x 2 halves)
    int q = t + i * 256;
    int sl = q >> 7, rem = q & 127;
    int r = rem >> 1, half = rem & 1;
    int gr = row0 + r; if (gr >= N_NODES) gr = N_NODES - 1;
    int s16 = sl * 2 + half;       // slot: cols s16*8..+7
    Hs[r * 16 + (s16 ^ (r & 7))] = Hg[(size_t)(sl * N_NODES + gr) * 2 + half];
  }
  const f16x8* Wg = (const f16x8*)Wt16;
  #pragma unroll
  for (int i = 0; i < 8; i++) {
    int q = t + i * 256;
    int c = q >> 4, s = q & 15;
    WtS[c * 16 + (s ^ (c & 7))] = Wg[(size_t)c * 16 + s];
  }
  __syncthreads();

  int wid = t >> 6, l = t & 63;
  int wrow = wid * 16;
  int lr = l & 15, lg = l >> 4;

  int r = wrow + lr, rx = r & 7, rbase = r * 16;
  f16x8 afr[4];
  #pragma unroll
  for (int kk = 0; kk < 4; kk++) afr[kk] = Hs[rbase + ((kk * 4 + lg) ^ rx)];

  f32x4 acc[8] = {};
  #pragma unroll
  for (int ct = 0; ct < 8; ct++) {
    int c = ct * 16 + lr, cx = c & 7, cbase = c * 16;
    #pragma unroll
    for (int kk = 0; kk < 4; kk++) {
      f16x8 bfr = WtS[cbase + ((kk * 4 + lg) ^ cx)];
      acc[ct] = __builtin_amdgcn_mfma_f32_16x16x32_f16(afr[kk], bfr, acc[ct], 0, 0, 0);
    }
  }

  int orow = row0 + wrow + lg * 4;
  #pragma unroll
  for (int i = 0; i < 4; i++) {
    int gr = orow + i;
    if (gr < N_NODES) {
      float dv = rsqrtf((float)(rowpack[gr] & 0x3FFF) + 1.0f);
      #pragma unroll
      for (int ct = 0; ct < 8; ct++)   // slice ct, 16 lanes -> 32 B contiguous
        HWS16[((size_t)ct * (N_NODES + 1) + gr) * 16 + lr] = (f16)(acc[ct][i] * dv);
    }
  }
}

// ---------------- gather + BN + ReLU (XCD-sharded column slices) ----------------
// slice = blockIdx%8 -> XCD via round-robin; per-XCD working set = (N+1)*32 B = 3.2 MB (L2-fits).
// 2 lanes per node (2 x f16x8), 32 nodes/wave, 128 nodes/block; MLP=8 edge loop as R11.

__global__ __launch_bounds__(256) void k_gslice(const f16* __restrict__ HWS,
                                                const int* __restrict__ rowpack,
                                                const int* __restrict__ col,
                                                const float* __restrict__ scsh,
                                                float* __restrict__ outF,
                                                f16* __restrict__ outH,
                                                int last) {
  int s = blockIdx.x & 7;
  int t = threadIdx.x;
  int wid = (blockIdx.x >> 3) * 128 + (t >> 1);
  int half = t & 1;
  if (wid >= N_NODES) return;
  int rp = rowpack[wid];
  int deg = rp & 0x3FFF;
  int off = rp >> 14;
  int pdeg = (deg + 3) & ~3;
  int beg = (wid >> BSHIFT) * CAP_C + off;
  const f16x8* h8 = (const f16x8*)HWS;
  size_t sbase = (size_t)s * (N_NODES + 1);

  f16x8 a0 = h8[(sbase + wid) * 2 + half];  // self row slice
  f16x8 a1 = {}, a2 = {}, a3 = {};
  int j = 0;
  for (; j + 8 <= pdeg; j += 8) {
    int4 c0 = *(const int4*)(col + beg + j);
    int4 c1 = *(const int4*)(col + beg + j + 4);
    f16x8 v0 = h8[(sbase + c0.x) * 2 + half];
    f16x8 v1 = h8[(sbase + c0.y) * 2 + half];
    f16x8 v2 = h8[(sbase + c0.z) * 2 + half];
    f16x8 v3 = h8[(sbase + c0.w) * 2 + half];
    f16x8 v4 = h8[(sbase + c1.x) * 2 + half];
    f16x8 v5 = h8[(sbase + c1.y) * 2 + half];
    f16x8 v6 = h8[(sbase + c1.z) * 2 + half];
    f16x8 v7 = h8[(sbase + c1.w) * 2 + half];
    a0 += v0; a1 += v1; a2 += v2; a3 += v3;
    a0 += v4; a1 += v5; a2 += v6; a3 += v7;
  }
  if (j < pdeg) {  // exactly one 4-batch
    int4 c0 = *(const int4*)(col + beg + j);
    f16x8 v0 = h8[(sbase + c0.x) * 2 + half];
    f16x8 v1 = h8[(sbase + c0.y) * 2 + half];
    f16x8 v2 = h8[(sbase + c0.z) * 2 + half];
    f16x8 v3 = h8[(sbase + c0.w) * 2 + half];
    a0 += v0; a1 += v1; a2 += v2; a3 += v3;
  }
  a0 += a1; a2 += a3; a0 += a2;

  float di = rsqrtf((float)(deg + 1));
  int c4 = s * 4 + half * 2;                  // f32x4 index into 128-col params
  const f32x4* scv = (const f32x4*)scsh;
  const f32x4* shv = (const f32x4*)(scsh + 128);
  float o[8];
  #pragma unroll
  for (int hh = 0; hh < 2; hh++) {
    f32x4 sc = scv[c4 + hh], sh = shv[c4 + hh];
    #pragma unroll
    for (int i = 0; i < 4; i++) {
      float v = (float)a0[hh * 4 + i] * di;
      o[hh * 4 + i] = fmaxf(fmaf(v, sc[i], sh[i]), 0.f);
    }
  }
  if (last) {
    f32x4* of = (f32x4*)outF;
    f32x4 lo = {o[0], o[1], o[2], o[3]}, hi = {o[4], o[5], o[6], o[7]};
    of[(size_t)wid * 32 + c4] = lo;
    of[(size_t)wid * 32 + c4 + 1] = hi;
  } else {
    f16x8 oh = {(f16)o[0], (f16)o[1], (f16)o[2], (f16)o[3],
                (f16)o[4], (f16)o[5], (f16)o[6], (f16)o[7]};
    ((f16x8*)outH)[(size_t)(s * N_NODES + wid) * 2 + half] = oh;
  }
}

// ---------------- launch ----------------

extern "C" void kernel_launch(void* const* d_in, const int* in_sizes, int n_in,
                              void* d_out, int out_size, void* d_ws, size_t ws_size,
                              hipStream_t stream) {
  const float* x = (const float*)d_in[0];
  const int* ei = (const int*)d_in[1];
  const int* srcv = ei;             // edge_index[0]
  const int* dstv = ei + N_EDGES;   // edge_index[1]
  const float* W     = (const float*)d_in[3];
  const float* b     = (const float*)d_in[4];
  const float* gamma = (const float*)d_in[5];
  const float* beta  = (const float*)d_in[6];
  const float* rmean = (const float*)d_in[7];
  const float* rvar  = (const float*)d_in[8];
  float* out = (float*)d_out;

  // workspace layout (bytes, 128-aligned)
  const size_t off_rowpack = 0;                       // N ints
  const size_t off_col     = 400128;                  // NB*CAP_C ints = 7,877,632
  const size_t off_scsh    = 400128 + 7877632;        // 3*256 floats
  const size_t off_wt      = off_scsh + 3072;         // 32 KB
  const size_t off_h16     = off_wt + 32768;          // 8*N*32 B = 25.6 MB (stage aliases)
  const size_t off_hws     = off_h16 + 25600000;      // 8*(N+1)*32 B
  const size_t need = off_hws + (size_t)NSL * (N_NODES + 1) * 32;  // ~59.5 MB
  if (ws_size < need) return;

  char* ws = (char*)d_ws;
  int*   rowpack = (int*)(ws + off_rowpack);
  int*   col     = (int*)(ws + off_col);
  float* scsh    = (float*)(ws + off_scsh);
  f16*   wt16    = (f16*)(ws + off_wt);
  f16*   h16     = (f16*)(ws + off_h16);
  int2*  stage   = (int2*)(ws + off_h16);   // 14.45 MB, dead before k_xslice
  f16*   hws16   = (f16*)(ws + off_hws);
  int*   bcnt    = (int*)(ws + off_hws);    // NB ints; disjoint from hws pad rows

  k_bzero<<<1, 256, 0, stream>>>(bcnt);
  k_binA<<<(N_EDGES + CHUNK - 1) / CHUNK, 256, 0, stream>>>(srcv, dstv, bcnt, stage);
  k_binB<<<NB, 512, 0, stream>>>(stage, bcnt, rowpack, col);
  k_xslice<<<782, 256, 0, stream>>>(x, h16);
  k_bnprep<<<1, 384, 0, stream>>>(b, gamma, beta, rmean, rvar, scsh);

  for (int l = 0; l < 3; l++) {
    k_wprep<<<64, 256, 0, stream>>>(W + l * DIM * DIM, wt16, hws16);
    k_gemm16<<<(N_NODES + BM - 1) / BM, 256, 0, stream>>>(h16, wt16, rowpack, hws16);
    k_gslice<<<8 * 782, 256, 0, stream>>>(hws16, rowpack, col, scsh + l * 256,
                                          out, h16, (l == 2) ? 1 : 0);
  }
}

// Round 13
// 321.074 us; speedup vs baseline: 1.0731x; 1.0731x over previous
//
#include <hip/hip_runtime.h>

#define N_NODES 100000
#define N_EDGES 1600000
#define DIM 128
#define BN_EPS 1e-5f
#define BSHIFT 9    // bucket = dst >> 9  (512 nodes/bucket)
#define BN 512      // nodes per bucket
#define NB 196      // ceil(N_NODES / BN)
#define CAP_S 9216  // staged edges per bucket (real; mean 8192, sigma ~90, +11s)
#define CAP_C 10048 // col entries per bucket (padded; mean ~8960, sigma ~93, +11s)
#define CHUNK 4096  // edges per phase-A block

typedef _Float16 f16;
typedef _Float16 f16x4 __attribute__((ext_vector_type(4)));
typedef _Float16 f16x8 __attribute__((ext_vector_type(8)));
typedef float f32x4 __attribute__((ext_vector_type(4)));

// ---------------- CSR build (R11, verbatim) ----------------

__global__ __launch_bounds__(256) void k_binA(const int* __restrict__ src,
                                              const int* __restrict__ dst,
                                              int* __restrict__ bcnt,
                                              int2* __restrict__ stage) {
  __shared__ int hist[NB];
  __shared__ int lofs[NB];
  __shared__ int lbase[NB];
  __shared__ int lcur[NB];
  __shared__ int scanbuf[256];
  __shared__ int2 buf[CHUNK];  // 32 KB
  int t = threadIdx.x;
  for (int i = t; i < NB; i += 256) { hist[i] = 0; lcur[i] = 0; }
  __syncthreads();
  int e0 = blockIdx.x * CHUNK;
  int en = min(CHUNK, N_EDGES - e0);
  for (int i = t; i < en; i += 256) {
    unsigned d = (unsigned)dst[e0 + i];
    unsigned s = (unsigned)src[e0 + i];
    if (d < N_NODES && s < N_NODES) atomicAdd(&hist[d >> BSHIFT], 1);
  }
  __syncthreads();
  scanbuf[t] = (t < NB) ? hist[t] : 0;
  __syncthreads();
  for (int off = 1; off < 256; off <<= 1) {
    int x = (t >= off) ? scanbuf[t - off] : 0;
    __syncthreads();
    scanbuf[t] += x;
    __syncthreads();
  }
  if (t < NB) {
    lofs[t] = scanbuf[t] - hist[t];
    lbase[t] = atomicAdd(&bcnt[t], hist[t]);
  }
  __syncthreads();
  for (int i = t; i < en; i += 256) {
    int d = dst[e0 + i], s = src[e0 + i];
    if ((unsigned)d < N_NODES && (unsigned)s < N_NODES) {
      int b = d >> BSHIFT;
      int r = atomicAdd(&lcur[b], 1);
      buf[lofs[b] + r] = make_int2(d, s);
    }
  }
  __syncthreads();
  int tot = lofs[NB - 1] + hist[NB - 1];
  for (int i = t; i < tot; i += 256) {
    int2 p = buf[i];
    int b = p.x >> BSHIFT;
    int goff = lbase[b] + (i - lofs[b]);
    if (goff < CAP_S) stage[(size_t)b * CAP_S + goff] = p;
  }
}

__global__ __launch_bounds__(512) void k_binB(const int2* __restrict__ stage,
                                              const int* __restrict__ bcnt,
                                              int* __restrict__ rowpack,
                                              int* __restrict__ col) {
  __shared__ int cnt[BN];
  __shared__ int offs[BN];
  __shared__ int lcur[BN];
  __shared__ int sb[BN];
  __shared__ int mp_s;
  __shared__ int colbuf[CAP_C];  // 40 KB
  int b = blockIdx.x, t = threadIdx.x;
  int base = b << BSHIFT;
  int nn = min(BN, N_NODES - base);
  int m = min(bcnt[b], CAP_S);
  const int2* seg = stage + (size_t)b * CAP_S;
  cnt[t] = 0; lcur[t] = 0;
  __syncthreads();
  for (int i = t; i < m; i += 512) atomicAdd(&cnt[seg[i].x - base], 1);
  __syncthreads();
  int pcnt = (cnt[t] + 3) & ~3;
  sb[t] = pcnt;
  __syncthreads();
  for (int off = 1; off < 512; off <<= 1) {
    int x = (t >= off) ? sb[t - off] : 0;
    __syncthreads();
    sb[t] += x;
    __syncthreads();
  }
  offs[t] = sb[t] - pcnt;
  if (t == 511) mp_s = sb[511];
  __syncthreads();
  for (int i = t; i < m; i += 512) {
    int2 p = seg[i];
    int dl = p.x - base;
    int r = atomicAdd(&lcur[dl], 1);
    int o = offs[dl] + r;
    if (o < CAP_C) colbuf[o] = p.y;
  }
  __syncthreads();
  {
    int o = offs[t], c = cnt[t], pc = (c + 3) & ~3;
    for (int k = c; k < pc; k++)
      if (o + k < CAP_C) colbuf[o + k] = N_NODES;
  }
  __syncthreads();
  if (t < nn) {
    int o = offs[t], c = cnt[t];
    if (o + ((c + 3) & ~3) > CAP_C) { o = 0; c = 0; }
    rowpack[base + t] = (o << 14) | c;
  }
  int mp = min(mp_s, CAP_C);
  for (int i = t; i < mp; i += 512) col[b * CAP_C + i] = colbuf[i];
}

// ---------------- prep: Wt (3 layers), BN fold, pad rows, bcnt zero ----------------

__global__ __launch_bounds__(256) void k_prep(const float* __restrict__ W,
                                              const float* __restrict__ bb,
                                              const float* __restrict__ gamma,
                                              const float* __restrict__ beta,
                                              const float* __restrict__ mean,
                                              const float* __restrict__ var,
                                              f16* __restrict__ wt,
                                              float* __restrict__ scsh,
                                              f16* __restrict__ hwsA,
                                              f16* __restrict__ hwsB,
                                              int* __restrict__ bcnt) {
  int tg = blockIdx.x * 256 + threadIdx.x;
  if (tg < 3 * DIM * DIM) {  // Wt[l][c][k] = W[l][k][c]
    int l = tg / (DIM * DIM), r = tg % (DIM * DIM);
    int c = r >> 7, k = r & 127;
    wt[tg] = (f16)W[l * DIM * DIM + k * DIM + c];
  }
  if (tg < 384) {
    int l = tg >> 7, c = tg & 127, i = l * DIM + c;
    float sc = gamma[i] * rsqrtf(var[i] + BN_EPS);
    scsh[l * 256 + c] = sc;
    scsh[l * 256 + 128 + c] = sc * (bb[i] - mean[i]) + beta[i];
  }
  if (tg >= 49152 && tg < 49152 + 32) {  // zero pad row N of both buffers
    int i = tg - 49152;
    f16x8 z = {};
    f16x8* p = (i < 16) ? (f16x8*)hwsA : (f16x8*)hwsB;
    p[(size_t)N_NODES * 16 + (i & 15)] = z;
  }
  if (tg >= 49184 && tg < 49184 + NB) bcnt[tg - 49184] = 0;
}

// ---------------- GEMM0: hws[r] = (x[r] @ W0) * dinv[r], x fp32 read directly ----------------

__global__ __launch_bounds__(256) void k_gemm0(const float* __restrict__ x,
                                               const f16* __restrict__ wt,
                                               const int* __restrict__ rowpack,
                                               f16* __restrict__ HWS) {
  __shared__ f16x8 Hs[64 * 16];    // 16 KB
  __shared__ f16x8 WtS[DIM * 16];  // 32 KB
  int t = threadIdx.x;
  int row0 = blockIdx.x * 64;
  const float4* xf = (const float4*)x;
  #pragma unroll
  for (int i = 0; i < 4; i++) {
    int q = t + i * 256;
    int r = q >> 4, s = q & 15;
    int gr = row0 + r; if (gr >= N_NODES) gr = N_NODES - 1;
    float4 u0 = xf[(size_t)gr * 32 + s * 2];
    float4 u1 = xf[(size_t)gr * 32 + s * 2 + 1];
    f16x8 o = {(f16)u0.x, (f16)u0.y, (f16)u0.z, (f16)u0.w,
               (f16)u1.x, (f16)u1.y, (f16)u1.z, (f16)u1.w};
    Hs[r * 16 + (s ^ (r & 7))] = o;
  }
  const f16x8* Wg = (const f16x8*)wt;
  #pragma unroll
  for (int i = 0; i < 8; i++) {
    int q = t + i * 256;
    int c = q >> 4, s = q & 15;
    WtS[c * 16 + (s ^ (c & 7))] = Wg[(size_t)c * 16 + s];
  }
  __syncthreads();

  int wid = t >> 6, l = t & 63;
  int wrow = wid * 16;
  int lr = l & 15, lg = l >> 4;
  int r = wrow + lr, rx = r & 7, rbase = r * 16;
  f16x8 afr[4];
  #pragma unroll
  for (int kk = 0; kk < 4; kk++) afr[kk] = Hs[rbase + ((kk * 4 + lg) ^ rx)];

  f32x4 acc[8] = {};
  #pragma unroll
  for (int ct = 0; ct < 8; ct++) {
    int c = ct * 16 + lr, cx = c & 7, cbase = c * 16;
    #pragma unroll
    for (int kk = 0; kk < 4; kk++) {
      f16x8 bfr = WtS[cbase + ((kk * 4 + lg) ^ cx)];
      acc[ct] = __builtin_amdgcn_mfma_f32_16x16x32_f16(afr[kk], bfr, acc[ct], 0, 0, 0);
    }
  }
  int orow = row0 + wrow + lg * 4;
  #pragma unroll
  for (int i = 0; i < 4; i++) {
    int gr = orow + i;
    if (gr < N_NODES) {
      float dv = rsqrtf((float)(rowpack[gr] & 0x3FFF) + 1.0f);
      #pragma unroll
      for (int ct = 0; ct < 8; ct++)
        HWS[(size_t)gr * DIM + ct * 16 + lr] = (f16)(acc[ct][i] * dv);
    }
  }
}

// ---------------- fused: gather(l)+BN+ReLU -> GEMM(l+1) -> hwsOut ----------------
// 64 nodes/block, 4 lanes/node (lane quarter qd owns cols qd*64..+63 = 4 f16x8 slots).
// Gather: MLP=8 (2 sources x 4 slots), dual fp16 accumulators. h' tile -> LDS (swizzled),
// then R11 MFMA compute; B-fragments read direct from L2-resident wt (no WtS -> 16 KB LDS).

__global__ __launch_bounds__(256) void k_fused(const f16* __restrict__ hwsIn,
                                               const f16* __restrict__ wt,
                                               const int* __restrict__ rowpack,
                                               const int* __restrict__ col,
                                               const float* __restrict__ scsh,
                                               f16* __restrict__ hwsOut) {
  __shared__ f16x8 Hs[64 * 16];  // 16 KB
  int t = threadIdx.x;
  int row = t >> 2;   // 0..63
  int qd = t & 3;
  int n = blockIdx.x * 64 + row;
  int rp = (n < N_NODES) ? rowpack[n] : 0;
  int deg = rp & 0x3FFF, off = rp >> 14;
  int pdeg = (deg + 3) & ~3;
  int beg = (n >> BSHIFT) * CAP_C + off;
  int selfrow = (n < N_NODES) ? n : N_NODES;
  const f16x8* h8 = (const f16x8*)hwsIn;

  size_t sbs = (size_t)selfrow * 16 + qd * 4;
  f16x8 aA0 = h8[sbs], aA1 = h8[sbs + 1], aA2 = h8[sbs + 2], aA3 = h8[sbs + 3];
  f16x8 aB0 = {}, aB1 = {}, aB2 = {}, aB3 = {};
  for (int j = 0; j + 2 <= pdeg; j += 2) {
    int2 c2 = *(const int2*)(col + beg + j);
    size_t b0 = (size_t)c2.x * 16 + qd * 4;
    size_t b1 = (size_t)c2.y * 16 + qd * 4;
    f16x8 v0 = h8[b0], v1 = h8[b0 + 1], v2 = h8[b0 + 2], v3 = h8[b0 + 3];
    f16x8 w0 = h8[b1], w1 = h8[b1 + 1], w2 = h8[b1 + 2], w3 = h8[b1 + 3];
    aA0 += v0; aA1 += v1; aA2 += v2; aA3 += v3;
    aB0 += w0; aB1 += w1; aB2 += w2; aB3 += w3;
  }
  aA0 += aB0; aA1 += aB1; aA2 += aB2; aA3 += aB3;

  float di = rsqrtf((float)(deg + 1));
  const f32x4* scv = (const f32x4*)scsh;
  const f32x4* shv = (const f32x4*)(scsh + 128);
  f16x8 accs[4] = {aA0, aA1, aA2, aA3};
  #pragma unroll
  for (int k = 0; k < 4; k++) {
    int s = qd * 4 + k;
    f32x4 sc0 = scv[s * 2], sh0 = shv[s * 2];
    f32x4 sc1 = scv[s * 2 + 1], sh1 = shv[s * 2 + 1];
    f16x8 o;
    #pragma unroll
    for (int i = 0; i < 4; i++)
      o[i] = (f16)fmaxf(fmaf((float)accs[k][i] * di, sc0[i], sh0[i]), 0.f);
    #pragma unroll
    for (int i = 0; i < 4; i++)
      o[4 + i] = (f16)fmaxf(fmaf((float)accs[k][4 + i] * di, sc1[i], sh1[i]), 0.f);
    Hs[row * 16 + (s ^ (row & 7))] = o;
  }
  __syncthreads();

  // GEMM phase (R11 compute; B direct from global wt)
  int wid = t >> 6, l = t & 63;
  int wrow = wid * 16;
  int lr = l & 15, lg = l >> 4;
  int r = wrow + lr, rx = r & 7, rbase = r * 16;
  f16x8 afr[4];
  #pragma unroll
  for (int kk = 0; kk < 4; kk++) afr[kk] = Hs[rbase + ((kk * 4 + lg) ^ rx)];

  const f16x8* Wg = (const f16x8*)wt;
  f32x4 acc[8] = {};
  #pragma unroll
  for (int ct = 0; ct < 8; ct++) {
    int c = ct * 16 + lr;
    #pragma unroll
    for (int kk = 0; kk < 4; kk++) {
      f16x8 bfr = Wg[(size_t)c * 16 + kk * 4 + lg];
      acc[ct] = __builtin_amdgcn_mfma_f32_16x16x32_f16(afr[kk], bfr, acc[ct], 0, 0, 0);
    }
  }
  int row0 = blockIdx.x * 64;
  int orow = row0 + wrow + lg * 4;
  #pragma unroll
  for (int i = 0; i < 4; i++) {
    int gr = orow + i;
    if (gr < N_NODES) {
      float dv = rsqrtf((float)(rowpack[gr] & 0x3FFF) + 1.0f);
      #pragma unroll
      for (int ct = 0; ct < 8; ct++)
        hwsOut[(size_t)gr * DIM + ct * 16 + lr] = (f16)(acc[ct][i] * dv);
    }
  }
}

// ---------------- final gather + BN + ReLU -> fp32 out (R11 k_gather8, fp32 path) ----------------

__global__ __launch_bounds__(256) void k_gatherout(const f16* __restrict__ HWS,
                                                   const int* __restrict__ rowpack,
                                                   const int* __restrict__ col,
                                                   const float* __restrict__ scsh,
                                                   float* __restrict__ outF) {
  int tid = blockIdx.x * 256 + threadIdx.x;
  int wid = tid >> 4;
  int cs = tid & 15;
  if (wid >= N_NODES) return;
  int rp = rowpack[wid];
  int deg = rp & 0x3FFF;
  int off = rp >> 14;
  int pdeg = (deg + 3) & ~3;
  int beg = (wid >> BSHIFT) * CAP_C + off;
  const f16x8* h8 = (const f16x8*)HWS;

  f16x8 a0 = h8[(size_t)wid * 16 + cs];
  f16x8 a1 = {}, a2 = {}, a3 = {};
  int j = 0;
  for (; j + 8 <= pdeg; j += 8) {
    int4 c0 = *(const int4*)(col + beg + j);
    int4 c1 = *(const int4*)(col + beg + j + 4);
    f16x8 v0 = h8[(size_t)c0.x * 16 + cs];
    f16x8 v1 = h8[(size_t)c0.y * 16 + cs];
    f16x8 v2 = h8[(size_t)c0.z * 16 + cs];
    f16x8 v3 = h8[(size_t)c0.w * 16 + cs];
    f16x8 v4 = h8[(size_t)c1.x * 16 + cs];
    f16x8 v5 = h8[(size_t)c1.y * 16 + cs];
    f16x8 v6 = h8[(size_t)c1.z * 16 + cs];
    f16x8 v7 = h8[(size_t)c1.w * 16 + cs];
    a0 += v0; a1 += v1; a2 += v2; a3 += v3;
    a0 += v4; a1 += v5; a2 += v6; a3 += v7;
  }
  if (j < pdeg) {
    int4 c0 = *(const int4*)(col + beg + j);
    f16x8 v0 = h8[(size_t)c0.x * 16 + cs];
    f16x8 v1 = h8[(size_t)c0.y * 16 + cs];
    f16x8 v2 = h8[(size_t)c0.z * 16 + cs];
    f16x8 v3 = h8[(size_t)c0.w * 16 + cs];
    a0 += v0; a1 += v1; a2 += v2; a3 += v3;
  }
  a0 += a1; a2 += a3; a0 += a2;

  float di = rsqrtf((float)(deg + 1));
  int c4 = cs * 2;
  const f32x4* scv = (const f32x4*)scsh;
  const f32x4* shv = (const f32x4*)(scsh + 128);
  float o[8];
  #pragma unroll
  for (int half = 0; half < 2; half++) {
    f32x4 sc = scv[c4 + half], sh = shv[c4 + half];
    #pragma unroll
    for (int i = 0; i < 4; i++) {
      float v = (float)a0[half * 4 + i] * di;
      o[half * 4 + i] = fmaxf(fmaf(v, sc[i], sh[i]), 0.f);
    }
  }
  f32x4* of = (f32x4*)outF;
  f32x4 lo = {o[0], o[1], o[2], o[3]}, hi = {o[4], o[5], o[6], o[7]};
  of[(size_t)wid * 32 + c4] = lo;
  of[(size_t)wid * 32 + c4 + 1] = hi;
}

// ---------------- launch ----------------

extern "C" void kernel_launch(void* const* d_in, const int* in_sizes, int n_in,
                              void* d_out, int out_size, void* d_ws, size_t ws_size,
                              hipStream_t stream) {
  const float* x = (const float*)d_in[0];
  const int* ei = (const int*)d_in[1];
  const int* srcv = ei;             // edge_index[0]
  const int* dstv = ei + N_EDGES;   // edge_index[1]
  const float* W     = (const float*)d_in[3];
  const float* b     = (const float*)d_in[4];
  const float* gamma = (const float*)d_in[5];
  const float* beta  = (const float*)d_in[6];
  const float* rmean = (const float*)d_in[7];
  const float* rvar  = (const float*)d_in[8];
  float* out = (float*)d_out;

  // workspace layout (bytes, 128-aligned)
  const size_t off_rowpack = 0;                        // N ints
  const size_t off_col     = 400128;                   // NB*CAP_C ints = 7,877,632
  const size_t off_scsh    = 400128 + 7877632;         // 3*256 floats
  const size_t off_wt      = off_scsh + 3072;          // 3*128*128 fp16 = 96 KB
  const size_t off_hwsB    = off_wt + 98304;           // (N+1)*256 B (stage aliases)
  const size_t off_hwsA    = off_hwsB + 25600256;      // (N+1)*256 B (bcnt aliases)
  const size_t need = off_hwsA + 25600256;             // ~59.6 MB
  if (ws_size < need) return;

  char* ws = (char*)d_ws;
  int*   rowpack = (int*)(ws + off_rowpack);
  int*   col     = (int*)(ws + off_col);
  float* scsh    = (float*)(ws + off_scsh);
  f16*   wt      = (f16*)(ws + off_wt);
  f16*   hwsB    = (f16*)(ws + off_hwsB);
  f16*   hwsA    = (f16*)(ws + off_hwsA);
  int2*  stage   = (int2*)(ws + off_hwsB);  // 14.45 MB; dead before fused1 writes hwsB
  int*   bcnt    = (int*)(ws + off_hwsA);   // 784 B; dead before gemm0 writes hwsA

  k_prep<<<193, 256, 0, stream>>>(W, b, gamma, beta, rmean, rvar,
                                  wt, scsh, hwsA, hwsB, bcnt);
  k_binA<<<(N_EDGES + CHUNK - 1) / CHUNK, 256, 0, stream>>>(srcv, dstv, bcnt, stage);
  k_binB<<<NB, 512, 0, stream>>>(stage, bcnt, rowpack, col);

  k_gemm0<<<1563, 256, 0, stream>>>(x, wt, rowpack, hwsA);
  k_fused<<<1563, 256, 0, stream>>>(hwsA, wt + DIM * DIM, rowpack, col,
                                    scsh, hwsB);           // gather L0 + BN0 + @W1
  k_fused<<<1563, 256, 0, stream>>>(hwsB, wt + 2 * DIM * DIM, rowpack, col,
                                    scsh + 256, hwsA);     // gather L1 + BN1 + @W2
  k_gatherout<<<6250, 256, 0, stream>>>(hwsA, rowpack, col, scsh + 512, out);
}

// Round 15
// 270.958 us; speedup vs baseline: 1.2715x; 1.1850x over previous
//
#include <hip/hip_runtime.h>

#define N_NODES 100000
#define N_EDGES 1600000
#define DIM 128
#define BN_EPS 1e-5f
#define BSHIFT 9    // bucket = dst >> 9  (512 nodes/bucket)
#define BN 512      // nodes per bucket
#define NB 196      // ceil(N_NODES / BN)
#define CAP_S 9216  // staged edges per bucket (real; mean 8192, sigma ~90, +11s)
#define CAP_C 10048 // col entries per bucket (padded; mean ~8960, sigma ~93, +11s)
#define CHUNK 4096  // edges per phase-A block

typedef _Float16 f16;
typedef _Float16 f16x4 __attribute__((ext_vector_type(4)));
typedef _Float16 f16x8 __attribute__((ext_vector_type(8)));
typedef float f32x4 __attribute__((ext_vector_type(4)));

// ---------------- CSR build (R11, verbatim) ----------------

__global__ __launch_bounds__(256) void k_binA(const int* __restrict__ src,
                                              const int* __restrict__ dst,
                                              int* __restrict__ bcnt,
                                              int2* __restrict__ stage) {
  __shared__ int hist[NB];
  __shared__ int lofs[NB];
  __shared__ int lbase[NB];
  __shared__ int lcur[NB];
  __shared__ int scanbuf[256];
  __shared__ int2 buf[CHUNK];  // 32 KB
  int t = threadIdx.x;
  for (int i = t; i < NB; i += 256) { hist[i] = 0; lcur[i] = 0; }
  __syncthreads();
  int e0 = blockIdx.x * CHUNK;
  int en = min(CHUNK, N_EDGES - e0);
  for (int i = t; i < en; i += 256) {
    unsigned d = (unsigned)dst[e0 + i];
    unsigned s = (unsigned)src[e0 + i];
    if (d < N_NODES && s < N_NODES) atomicAdd(&hist[d >> BSHIFT], 1);
  }
  __syncthreads();
  scanbuf[t] = (t < NB) ? hist[t] : 0;
  __syncthreads();
  for (int off = 1; off < 256; off <<= 1) {
    int x = (t >= off) ? scanbuf[t - off] : 0;
    __syncthreads();
    scanbuf[t] += x;
    __syncthreads();
  }
  if (t < NB) {
    lofs[t] = scanbuf[t] - hist[t];
    lbase[t] = atomicAdd(&bcnt[t], hist[t]);
  }
  __syncthreads();
  for (int i = t; i < en; i += 256) {
    int d = dst[e0 + i], s = src[e0 + i];
    if ((unsigned)d < N_NODES && (unsigned)s < N_NODES) {
      int b = d >> BSHIFT;
      int r = atomicAdd(&lcur[b], 1);
      buf[lofs[b] + r] = make_int2(d, s);
    }
  }
  __syncthreads();
  int tot = lofs[NB - 1] + hist[NB - 1];
  for (int i = t; i < tot; i += 256) {
    int2 p = buf[i];
    int b = p.x >> BSHIFT;
    int goff = lbase[b] + (i - lofs[b]);
    if (goff < CAP_S) stage[(size_t)b * CAP_S + goff] = p;
  }
}

__global__ __launch_bounds__(512) void k_binB(const int2* __restrict__ stage,
                                              const int* __restrict__ bcnt,
                                              int* __restrict__ rowpack,
                                              int* __restrict__ col) {
  __shared__ int cnt[BN];
  __shared__ int offs[BN];
  __shared__ int lcur[BN];
  __shared__ int sb[BN];
  __shared__ int mp_s;
  __shared__ int colbuf[CAP_C];  // 40 KB
  int b = blockIdx.x, t = threadIdx.x;
  int base = b << BSHIFT;
  int nn = min(BN, N_NODES - base);
  int m = min(bcnt[b], CAP_S);
  const int2* seg = stage + (size_t)b * CAP_S;
  cnt[t] = 0; lcur[t] = 0;
  __syncthreads();
  for (int i = t; i < m; i += 512) atomicAdd(&cnt[seg[i].x - base], 1);
  __syncthreads();
  int pcnt = (cnt[t] + 3) & ~3;
  sb[t] = pcnt;
  __syncthreads();
  for (int off = 1; off < 512; off <<= 1) {
    int x = (t >= off) ? sb[t - off] : 0;
    __syncthreads();
    sb[t] += x;
    __syncthreads();
  }
  offs[t] = sb[t] - pcnt;
  if (t == 511) mp_s = sb[511];
  __syncthreads();
  for (int i = t; i < m; i += 512) {
    int2 p = seg[i];
    int dl = p.x - base;
    int r = atomicAdd(&lcur[dl], 1);
    int o = offs[dl] + r;
    if (o < CAP_C) colbuf[o] = p.y;
  }
  __syncthreads();
  {
    int o = offs[t], c = cnt[t], pc = (c + 3) & ~3;
    for (int k = c; k < pc; k++)
      if (o + k < CAP_C) colbuf[o + k] = N_NODES;
  }
  __syncthreads();
  if (t < nn) {
    int o = offs[t], c = cnt[t];
    if (o + ((c + 3) & ~3) > CAP_C) { o = 0; c = 0; }
    rowpack[base + t] = (o << 14) | c;
  }
  int mp = min(mp_s, CAP_C);
  for (int i = t; i < mp; i += 512) col[b * CAP_C + i] = colbuf[i];
}

// ---------------- prep: Wt (3 layers), BN fold, hws pad row, bcnt zero ----------------

__global__ __launch_bounds__(256) void k_prep(const float* __restrict__ W,
                                              const float* __restrict__ bb,
                                              const float* __restrict__ gamma,
                                              const float* __restrict__ beta,
                                              const float* __restrict__ mean,
                                              const float* __restrict__ var,
                                              f16* __restrict__ wt,
                                              float* __restrict__ scsh,
                                              f16* __restrict__ hws,
                                              int* __restrict__ bcnt) {
  int tg = blockIdx.x * 256 + threadIdx.x;
  if (tg < 3 * DIM * DIM) {  // Wt[l][c][k] = W[l][k][c]
    int l = tg / (DIM * DIM), r = tg % (DIM * DIM);
    int c = r >> 7, k = r & 127;
    wt[tg] = (f16)W[l * DIM * DIM + k * DIM + c];
  }
  if (tg < 384) {
    int l = tg >> 7, c = tg & 127, i = l * DIM + c;
    float sc = gamma[i] * rsqrtf(var[i] + BN_EPS);
    scsh[l * 256 + c] = sc;
    scsh[l * 256 + 128 + c] = sc * (bb[i] - mean[i]) + beta[i];
  }
  if (tg >= 49152 && tg < 49152 + 16) {  // zero pad row N of hws
    f16x8 z = {};
    ((f16x8*)hws)[(size_t)N_NODES * 16 + (tg - 49152)] = z;
  }
  if (tg >= 49184 && tg < 49184 + NB) bcnt[tg - 49184] = 0;
}

// ---------------- GEMM0: hws[r] = (x[r] @ W0) * dinv[r], x fp32 read directly ----------------

__global__ __launch_bounds__(256) void k_gemm0(const float* __restrict__ x,
                                               const f16* __restrict__ wt,
                                               const int* __restrict__ rowpack,
                                               f16* __restrict__ HWS) {
  __shared__ f16x8 Hs[64 * 16];    // 16 KB
  __shared__ f16x8 WtS[DIM * 16];  // 32 KB
  int t = threadIdx.x;
  int row0 = blockIdx.x * 64;
  const float4* xf = (const float4*)x;
  #pragma unroll
  for (int i = 0; i < 4; i++) {
    int q = t + i * 256;
    int r = q >> 4, s = q & 15;
    int gr = row0 + r; if (gr >= N_NODES) gr = N_NODES - 1;
    float4 u0 = xf[(size_t)gr * 32 + s * 2];
    float4 u1 = xf[(size_t)gr * 32 + s * 2 + 1];
    f16x8 o = {(f16)u0.x, (f16)u0.y, (f16)u0.z, (f16)u0.w,
               (f16)u1.x, (f16)u1.y, (f16)u1.z, (f16)u1.w};
    Hs[r * 16 + (s ^ (r & 7))] = o;
  }
  const f16x8* Wg = (const f16x8*)wt;
  #pragma unroll
  for (int i = 0; i < 8; i++) {
    int q = t + i * 256;
    int c = q >> 4, s = q & 15;
    WtS[c * 16 + (s ^ (c & 7))] = Wg[(size_t)c * 16 + s];
  }
  __syncthreads();

  int wid = t >> 6, l = t & 63;
  int wrow = wid * 16;
  int lr = l & 15, lg = l >> 4;
  int r = wrow + lr, rx = r & 7, rbase = r * 16;
  f16x8 afr[4];
  #pragma unroll
  for (int kk = 0; kk < 4; kk++) afr[kk] = Hs[rbase + ((kk * 4 + lg) ^ rx)];

  f32x4 acc[8] = {};
  #pragma unroll
  for (int ct = 0; ct < 8; ct++) {
    int c = ct * 16 + lr, cx = c & 7, cbase = c * 16;
    #pragma unroll
    for (int kk = 0; kk < 4; kk++) {
      f16x8 bfr = WtS[cbase + ((kk * 4 + lg) ^ cx)];
      acc[ct] = __builtin_amdgcn_mfma_f32_16x16x32_f16(afr[kk], bfr, acc[ct], 0, 0, 0);
    }
  }
  int orow = row0 + wrow + lg * 4;
  #pragma unroll
  for (int i = 0; i < 4; i++) {
    int gr = orow + i;
    if (gr < N_NODES) {
      float dv = rsqrtf((float)(rowpack[gr] & 0x3FFF) + 1.0f);
      #pragma unroll
      for (int ct = 0; ct < 8; ct++)
        HWS[(size_t)gr * DIM + ct * 16 + lr] = (f16)(acc[ct][i] * dv);
    }
  }
}

// ---------------- GEMM (layers 1,2): hws[r] = (h16[r] @ Wl) * dinv[r] ----------------

__global__ __launch_bounds__(256) void k_gemm16(const f16* __restrict__ H16,
                                                const f16* __restrict__ wt,
                                                const int* __restrict__ rowpack,
                                                f16* __restrict__ HWS) {
  __shared__ f16x8 Hs[64 * 16];    // 16 KB
  __shared__ f16x8 WtS[DIM * 16];  // 32 KB
  int t = threadIdx.x;
  int row0 = blockIdx.x * 64;

  const f16x8* Hg = (const f16x8*)H16;
  #pragma unroll
  for (int i = 0; i < 4; i++) {
    int q = t + i * 256;
    int r = q >> 4, s = q & 15;
    int gr = row0 + r; if (gr >= N_NODES) gr = N_NODES - 1;
    Hs[r * 16 + (s ^ (r & 7))] = Hg[(size_t)gr * 16 + s];
  }
  const f16x8* Wg = (const f16x8*)wt;
  #pragma unroll
  for (int i = 0; i < 8; i++) {
    int q = t + i * 256;
    int c = q >> 4, s = q & 15;
    WtS[c * 16 + (s ^ (c & 7))] = Wg[(size_t)c * 16 + s];
  }
  __syncthreads();

  int wid = t >> 6, l = t & 63;
  int wrow = wid * 16;
  int lr = l & 15, lg = l >> 4;
  int r = wrow + lr, rx = r & 7, rbase = r * 16;
  f16x8 afr[4];
  #pragma unroll
  for (int kk = 0; kk < 4; kk++) afr[kk] = Hs[rbase + ((kk * 4 + lg) ^ rx)];

  f32x4 acc[8] = {};
  #pragma unroll
  for (int ct = 0; ct < 8; ct++) {
    int c = ct * 16 + lr, cx = c & 7, cbase = c * 16;
    #pragma unroll
    for (int kk = 0; kk < 4; kk++) {
      f16x8 bfr = WtS[cbase + ((kk * 4 + lg) ^ cx)];
      acc[ct] = __builtin_amdgcn_mfma_f32_16x16x32_f16(afr[kk], bfr, acc[ct], 0, 0, 0);
    }
  }
  int orow = row0 + wrow + lg * 4;
  #pragma unroll
  for (int i = 0; i < 4; i++) {
    int gr = orow + i;
    if (gr < N_NODES) {
      float dv = rsqrtf((float)(rowpack[gr] & 0x3FFF) + 1.0f);
      #pragma unroll
      for (int ct = 0; ct < 8; ct++)
        HWS[(size_t)gr * DIM + ct * 16 + lr] = (f16)(acc[ct][i] * dv);
    }
  }
}

// ---------------- gather + BN + ReLU (16-lane group/node, MLP=16) ----------------

__global__ __launch_bounds__(256) void k_gather16(const f16* __restrict__ HWS,
                                                  const int* __restrict__ rowpack,
                                                  const int* __restrict__ col,
                                                  const float* __restrict__ scsh,
                                                  float* __restrict__ outF,
                                                  f16* __restrict__ outH,
                                                  int last) {
  int tid = blockIdx.x * 256 + threadIdx.x;
  int wid = tid >> 4;
  int cs = tid & 15;
  if (wid >= N_NODES) return;
  int rp = rowpack[wid];
  int deg = rp & 0x3FFF;
  int off = rp >> 14;
  int pdeg = (deg + 3) & ~3;
  int beg = (wid >> BSHIFT) * CAP_C + off;
  const f16x8* h8 = (const f16x8*)HWS;

  f16x8 a0 = h8[(size_t)wid * 16 + cs];  // self row
  f16x8 a1 = {}, a2 = {}, a3 = {};
  int j = 0;
  for (; j + 16 <= pdeg; j += 16) {
    int4 c0 = *(const int4*)(col + beg + j);
    int4 c1 = *(const int4*)(col + beg + j + 4);
    int4 c2 = *(const int4*)(col + beg + j + 8);
    int4 c3 = *(const int4*)(col + beg + j + 12);
    f16x8 v0 = h8[(size_t)c0.x * 16 + cs];
    f16x8 v1 = h8[(size_t)c0.y * 16 + cs];
    f16x8 v2 = h8[(size_t)c0.z * 16 + cs];
    f16x8 v3 = h8[(size_t)c0.w * 16 + cs];
    f16x8 v4 = h8[(size_t)c1.x * 16 + cs];
    f16x8 v5 = h8[(size_t)c1.y * 16 + cs];
    f16x8 v6 = h8[(size_t)c1.z * 16 + cs];
    f16x8 v7 = h8[(size_t)c1.w * 16 + cs];
    f16x8 v8 = h8[(size_t)c2.x * 16 + cs];
    f16x8 v9 = h8[(size_t)c2.y * 16 + cs];
    f16x8 va = h8[(size_t)c2.z * 16 + cs];
    f16x8 vb = h8[(size_t)c2.w * 16 + cs];
    f16x8 vc = h8[(size_t)c3.x * 16 + cs];
    f16x8 vd = h8[(size_t)c3.y * 16 + cs];
    f16x8 ve = h8[(size_t)c3.z * 16 + cs];
    f16x8 vf = h8[(size_t)c3.w * 16 + cs];
    a0 += v0; a1 += v1; a2 += v2; a3 += v3;
    a0 += v4; a1 += v5; a2 += v6; a3 += v7;
    a0 += v8; a1 += v9; a2 += va; a3 += vb;
    a0 += vc; a1 += vd; a2 += ve; a3 += vf;
  }
  if (j + 8 <= pdeg) {
    int4 c0 = *(const int4*)(col + beg + j);
    int4 c1 = *(const int4*)(col + beg + j + 4);
    f16x8 v0 = h8[(size_t)c0.x * 16 + cs];
    f16x8 v1 = h8[(size_t)c0.y * 16 + cs];
    f16x8 v2 = h8[(size_t)c0.z * 16 + cs];
    f16x8 v3 = h8[(size_t)c0.w * 16 + cs];
    f16x8 v4 = h8[(size_t)c1.x * 16 + cs];
    f16x8 v5 = h8[(size_t)c1.y * 16 + cs];
    f16x8 v6 = h8[(size_t)c1.z * 16 + cs];
    f16x8 v7 = h8[(size_t)c1.w * 16 + cs];
    a0 += v0; a1 += v1; a2 += v2; a3 += v3;
    a0 += v4; a1 += v5; a2 += v6; a3 += v7;
    j += 8;
  }
  if (j < pdeg) {
    int4 c0 = *(const int4*)(col + beg + j);
    f16x8 v0 = h8[(size_t)c0.x * 16 + cs];
    f16x8 v1 = h8[(size_t)c0.y * 16 + cs];
    f16x8 v2 = h8[(size_t)c0.z * 16 + cs];
    f16x8 v3 = h8[(size_t)c0.w * 16 + cs];
    a0 += v0; a1 += v1; a2 += v2; a3 += v3;
  }
  a0 += a1; a2 += a3; a0 += a2;

  float di = rsqrtf((float)(deg + 1));
  int c4 = cs * 2;
  const f32x4* scv = (const f32x4*)scsh;
  const f32x4* shv = (const f32x4*)(scsh + 128);
  float o[8];
  #pragma unroll
  for (int half = 0; half < 2; half++) {
    f32x4 sc = scv[c4 + half], sh = shv[c4 + half];
    #pragma unroll
    for (int i = 0; i < 4; i++) {
      float v = (float)a0[half * 4 + i] * di;
      o[half * 4 + i] = fmaxf(fmaf(v, sc[i], sh[i]), 0.f);
    }
  }
  if (last) {
    f32x4* of = (f32x4*)outF;
    f32x4 lo = {o[0], o[1], o[2], o[3]}, hi = {o[4], o[5], o[6], o[7]};
    of[(size_t)wid * 32 + c4] = lo;
    of[(size_t)wid * 32 + c4 + 1] = hi;
  } else {
    f16x8 oh = {(f16)o[0], (f16)o[1], (f16)o[2], (f16)o[3],
                (f16)o[4], (f16)o[5], (f16)o[6], (f16)o[7]};
    ((f16x8*)outH)[(size_t)wid * 16 + cs] = oh;
  }
}

// ---------------- launch ----------------

extern "C" void kernel_launch(void* const* d_in, const int* in_sizes, int n_in,
                              void* d_out, int out_size, void* d_ws, size_t ws_size,
                              hipStream_t stream) {
  const float* x = (const float*)d_in[0];
  const int* ei = (const int*)d_in[1];
  const int* srcv = ei;             // edge_index[0]
  const int* dstv = ei + N_EDGES;   // edge_index[1]
  const float* W     = (const float*)d_in[3];
  const float* b     = (const float*)d_in[4];
  const float* gamma = (const float*)d_in[5];
  const float* beta  = (const float*)d_in[6];
  const float* rmean = (const float*)d_in[7];
  const float* rvar  = (const float*)d_in[8];
  float* out = (float*)d_out;

  // workspace layout (bytes, 128-aligned)
  const size_t off_rowpack = 0;                        // N ints
  const size_t off_col     = 400128;                   // NB*CAP_C ints = 7,877,632
  const size_t off_scsh    = 400128 + 7877632;         // 3*256 floats
  const size_t off_wt      = off_scsh + 3072;          // 3*128*128 fp16 = 96 KB
  const size_t off_h16     = off_wt + 98304;           // N*256 B (stage aliases)
  const size_t off_hws     = off_h16 + 25600000;       // (N+1)*256 B (bcnt aliases)
  const size_t need = off_hws + 25600256;              // ~59.6 MB
  if (ws_size < need) return;

  char* ws = (char*)d_ws;
  int*   rowpack = (int*)(ws + off_rowpack);
  int*   col     = (int*)(ws + off_col);
  float* scsh    = (float*)(ws + off_scsh);
  f16*   wt      = (f16*)(ws + off_wt);
  f16*   h16     = (f16*)(ws + off_h16);
  f16*   hws     = (f16*)(ws + off_hws);
  int2*  stage   = (int2*)(ws + off_h16);   // 14.45 MB; dead before gather L0 writes h16
  int*   bcnt    = (int*)(ws + off_hws);    // 784 B; dead before gemm0 writes hws

  k_prep<<<193, 256, 0, stream>>>(W, b, gamma, beta, rmean, rvar, wt, scsh, hws, bcnt);
  k_binA<<<(N_EDGES + CHUNK - 1) / CHUNK, 256, 0, stream>>>(srcv, dstv, bcnt, stage);
  k_binB<<<NB, 512, 0, stream>>>(stage, bcnt, rowpack, col);

  k_gemm0<<<1563, 256, 0, stream>>>(x, wt, rowpack, hws);
  k_gather16<<<6250, 256, 0, stream>>>(hws, rowpack, col, scsh, out, h16, 0);
  k_gemm16<<<1563, 256, 0, stream>>>(h16, wt + DIM * DIM, rowpack, hws);
  k_gather16<<<6250, 256, 0, stream>>>(hws, rowpack, col, scsh + 256, out, h16, 0);
  k_gemm16<<<1563, 256, 0, stream>>>(h16, wt + 2 * DIM * DIM, rowpack, hws);
  k_gather16<<<6250, 256, 0, stream>>>(hws, rowpack, col, scsh + 512, out, h16, 1);
}

// Round 16
// 264.608 us; speedup vs baseline: 1.3020x; 1.0240x over previous
//
#include <hip/hip_runtime.h>

#define N_NODES 100000
#define N_EDGES 1600000
#define DIM 128
#define BN_EPS 1e-5f
#define BSHIFT 9    // bucket = dst >> 9  (512 nodes/bucket)
#define BN 512      // nodes per bucket
#define NB 196      // ceil(N_NODES / BN)
#define CAP_S 9216  // staged edges per bucket (real; mean 8192, sigma ~90, +11s)
#define CAP_C 10048 // col entries per bucket (padded; mean ~8960, sigma ~93, +11s)
#define CHUNK 4096  // edges per phase-A block

typedef _Float16 f16;
typedef _Float16 f16x4 __attribute__((ext_vector_type(4)));
typedef _Float16 f16x8 __attribute__((ext_vector_type(8)));
typedef float f32x4 __attribute__((ext_vector_type(4)));

// ---------------- CSR build (R11, verbatim) ----------------

__global__ __launch_bounds__(256) void k_binA(const int* __restrict__ src,
                                              const int* __restrict__ dst,
                                              int* __restrict__ bcnt,
                                              int2* __restrict__ stage) {
  __shared__ int hist[NB];
  __shared__ int lofs[NB];
  __shared__ int lbase[NB];
  __shared__ int lcur[NB];
  __shared__ int scanbuf[256];
  __shared__ int2 buf[CHUNK];  // 32 KB
  int t = threadIdx.x;
  for (int i = t; i < NB; i += 256) { hist[i] = 0; lcur[i] = 0; }
  __syncthreads();
  int e0 = blockIdx.x * CHUNK;
  int en = min(CHUNK, N_EDGES - e0);
  for (int i = t; i < en; i += 256) {
    unsigned d = (unsigned)dst[e0 + i];
    unsigned s = (unsigned)src[e0 + i];
    if (d < N_NODES && s < N_NODES) atomicAdd(&hist[d >> BSHIFT], 1);
  }
  __syncthreads();
  scanbuf[t] = (t < NB) ? hist[t] : 0;
  __syncthreads();
  for (int off = 1; off < 256; off <<= 1) {
    int x = (t >= off) ? scanbuf[t - off] : 0;
    __syncthreads();
    scanbuf[t] += x;
    __syncthreads();
  }
  if (t < NB) {
    lofs[t] = scanbuf[t] - hist[t];
    lbase[t] = atomicAdd(&bcnt[t], hist[t]);
  }
  __syncthreads();
  for (int i = t; i < en; i += 256) {
    int d = dst[e0 + i], s = src[e0 + i];
    if ((unsigned)d < N_NODES && (unsigned)s < N_NODES) {
      int b = d >> BSHIFT;
      int r = atomicAdd(&lcur[b], 1);
      buf[lofs[b] + r] = make_int2(d, s);
    }
  }
  __syncthreads();
  int tot = lofs[NB - 1] + hist[NB - 1];
  for (int i = t; i < tot; i += 256) {
    int2 p = buf[i];
    int b = p.x >> BSHIFT;
    int goff = lbase[b] + (i - lofs[b]);
    if (goff < CAP_S) stage[(size_t)b * CAP_S + goff] = p;
  }
}

__global__ __launch_bounds__(512) void k_binB(const int2* __restrict__ stage,
                                              const int* __restrict__ bcnt,
                                              int* __restrict__ rowpack,
                                              int* __restrict__ col) {
  __shared__ int cnt[BN];
  __shared__ int offs[BN];
  __shared__ int lcur[BN];
  __shared__ int sb[BN];
  __shared__ int mp_s;
  __shared__ int colbuf[CAP_C];  // 40 KB
  int b = blockIdx.x, t = threadIdx.x;
  int base = b << BSHIFT;
  int nn = min(BN, N_NODES - base);
  int m = min(bcnt[b], CAP_S);
  const int2* seg = stage + (size_t)b * CAP_S;
  cnt[t] = 0; lcur[t] = 0;
  __syncthreads();
  for (int i = t; i < m; i += 512) atomicAdd(&cnt[seg[i].x - base], 1);
  __syncthreads();
  int pcnt = (cnt[t] + 3) & ~3;
  sb[t] = pcnt;
  __syncthreads();
  for (int off = 1; off < 512; off <<= 1) {
    int x = (t >= off) ? sb[t - off] : 0;
    __syncthreads();
    sb[t] += x;
    __syncthreads();
  }
  offs[t] = sb[t] - pcnt;
  if (t == 511) mp_s = sb[511];
  __syncthreads();
  for (int i = t; i < m; i += 512) {
    int2 p = seg[i];
    int dl = p.x - base;
    int r = atomicAdd(&lcur[dl], 1);
    int o = offs[dl] + r;
    if (o < CAP_C) colbuf[o] = p.y;
  }
  __syncthreads();
  {
    int o = offs[t], c = cnt[t], pc = (c + 3) & ~3;
    for (int k = c; k < pc; k++)
      if (o + k < CAP_C) colbuf[o + k] = N_NODES;
  }
  __syncthreads();
  if (t < nn) {
    int o = offs[t], c = cnt[t];
    if (o + ((c + 3) & ~3) > CAP_C) { o = 0; c = 0; }
    rowpack[base + t] = (o << 14) | c;
  }
  int mp = min(mp_s, CAP_C);
  for (int i = t; i < mp; i += 512) col[b * CAP_C + i] = colbuf[i];
}

// ---------------- prep: Wt (3 layers), BN fold, hws pad row, bcnt zero ----------------

__global__ __launch_bounds__(256) void k_prep(const float* __restrict__ W,
                                              const float* __restrict__ bb,
                                              const float* __restrict__ gamma,
                                              const float* __restrict__ beta,
                                              const float* __restrict__ mean,
                                              const float* __restrict__ var,
                                              f16* __restrict__ wt,
                                              float* __restrict__ scsh,
                                              f16* __restrict__ hws,
                                              int* __restrict__ bcnt) {
  int tg = blockIdx.x * 256 + threadIdx.x;
  if (tg < 3 * DIM * DIM) {  // Wt[l][c][k] = W[l][k][c]
    int l = tg / (DIM * DIM), r = tg % (DIM * DIM);
    int c = r >> 7, k = r & 127;
    wt[tg] = (f16)W[l * DIM * DIM + k * DIM + c];
  }
  if (tg < 384) {
    int l = tg >> 7, c = tg & 127, i = l * DIM + c;
    float sc = gamma[i] * rsqrtf(var[i] + BN_EPS);
    scsh[l * 256 + c] = sc;
    scsh[l * 256 + 128 + c] = sc * (bb[i] - mean[i]) + beta[i];
  }
  if (tg >= 49152 && tg < 49152 + 16) {  // zero pad row N of hws
    f16x8 z = {};
    ((f16x8*)hws)[(size_t)N_NODES * 16 + (tg - 49152)] = z;
  }
  if (tg >= 49184 && tg < 49184 + NB) bcnt[tg - 49184] = 0;
}

// ---------------- GEMM0: hws[r] = (x[r] @ W0) * dinv[r], x fp32 read directly ----------------

__global__ __launch_bounds__(256) void k_gemm0(const float* __restrict__ x,
                                               const f16* __restrict__ wt,
                                               const int* __restrict__ rowpack,
                                               f16* __restrict__ HWS) {
  __shared__ f16x8 Hs[64 * 16];    // 16 KB
  __shared__ f16x8 WtS[DIM * 16];  // 32 KB
  int t = threadIdx.x;
  int row0 = blockIdx.x * 64;
  const float4* xf = (const float4*)x;
  #pragma unroll
  for (int i = 0; i < 4; i++) {
    int q = t + i * 256;
    int r = q >> 4, s = q & 15;
    int gr = row0 + r; if (gr >= N_NODES) gr = N_NODES - 1;
    float4 u0 = xf[(size_t)gr * 32 + s * 2];
    float4 u1 = xf[(size_t)gr * 32 + s * 2 + 1];
    f16x8 o = {(f16)u0.x, (f16)u0.y, (f16)u0.z, (f16)u0.w,
               (f16)u1.x, (f16)u1.y, (f16)u1.z, (f16)u1.w};
    Hs[r * 16 + (s ^ (r & 7))] = o;
  }
  const f16x8* Wg = (const f16x8*)wt;
  #pragma unroll
  for (int i = 0; i < 8; i++) {
    int q = t + i * 256;
    int c = q >> 4, s = q & 15;
    WtS[c * 16 + (s ^ (c & 7))] = Wg[(size_t)c * 16 + s];
  }
  __syncthreads();

  int wid = t >> 6, l = t & 63;
  int wrow = wid * 16;
  int lr = l & 15, lg = l >> 4;
  int r = wrow + lr, rx = r & 7, rbase = r * 16;
  f16x8 afr[4];
  #pragma unroll
  for (int kk = 0; kk < 4; kk++) afr[kk] = Hs[rbase + ((kk * 4 + lg) ^ rx)];

  f32x4 acc[8] = {};
  #pragma unroll
  for (int ct = 0; ct < 8; ct++) {
    int c = ct * 16 + lr, cx = c & 7, cbase = c * 16;
    #pragma unroll
    for (int kk = 0; kk < 4; kk++) {
      f16x8 bfr = WtS[cbase + ((kk * 4 + lg) ^ cx)];
      acc[ct] = __builtin_amdgcn_mfma_f32_16x16x32_f16(afr[kk], bfr, acc[ct], 0, 0, 0);
    }
  }
  int orow = row0 + wrow + lg * 4;
  #pragma unroll
  for (int i = 0; i < 4; i++) {
    int gr = orow + i;
    if (gr < N_NODES) {
      float dv = rsqrtf((float)(rowpack[gr] & 0x3FFF) + 1.0f);
      #pragma unroll
      for (int ct = 0; ct < 8; ct++)
        HWS[(size_t)gr * DIM + ct * 16 + lr] = (f16)(acc[ct][i] * dv);
    }
  }
}

// ---------------- GEMM (layers 1,2): hws[r] = (h16[r] @ Wl) * dinv[r] ----------------

__global__ __launch_bounds__(256) void k_gemm16(const f16* __restrict__ H16,
                                                const f16* __restrict__ wt,
                                                const int* __restrict__ rowpack,
                                                f16* __restrict__ HWS) {
  __shared__ f16x8 Hs[64 * 16];    // 16 KB
  __shared__ f16x8 WtS[DIM * 16];  // 32 KB
  int t = threadIdx.x;
  int row0 = blockIdx.x * 64;

  const f16x8* Hg = (const f16x8*)H16;
  #pragma unroll
  for (int i = 0; i < 4; i++) {
    int q = t + i * 256;
    int r = q >> 4, s = q & 15;
    int gr = row0 + r; if (gr >= N_NODES) gr = N_NODES - 1;
    Hs[r * 16 + (s ^ (r & 7))] = Hg[(size_t)gr * 16 + s];
  }
  const f16x8* Wg = (const f16x8*)wt;
  #pragma unroll
  for (int i = 0; i < 8; i++) {
    int q = t + i * 256;
    int c = q >> 4, s = q & 15;
    WtS[c * 16 + (s ^ (c & 7))] = Wg[(size_t)c * 16 + s];
  }
  __syncthreads();

  int wid = t >> 6, l = t & 63;
  int wrow = wid * 16;
  int lr = l & 15, lg = l >> 4;
  int r = wrow + lr, rx = r & 7, rbase = r * 16;
  f16x8 afr[4];
  #pragma unroll
  for (int kk = 0; kk < 4; kk++) afr[kk] = Hs[rbase + ((kk * 4 + lg) ^ rx)];

  f32x4 acc[8] = {};
  #pragma unroll
  for (int ct = 0; ct < 8; ct++) {
    int c = ct * 16 + lr, cx = c & 7, cbase = c * 16;
    #pragma unroll
    for (int kk = 0; kk < 4; kk++) {
      f16x8 bfr = WtS[cbase + ((kk * 4 + lg) ^ cx)];
      acc[ct] = __builtin_amdgcn_mfma_f32_16x16x32_f16(afr[kk], bfr, acc[ct], 0, 0, 0);
    }
  }
  int orow = row0 + wrow + lg * 4;
  #pragma unroll
  for (int i = 0; i < 4; i++) {
    int gr = orow + i;
    if (gr < N_NODES) {
      float dv = rsqrtf((float)(rowpack[gr] & 0x3FFF) + 1.0f);
      #pragma unroll
      for (int ct = 0; ct < 8; ct++)
        HWS[(size_t)gr * DIM + ct * 16 + lr] = (f16)(acc[ct][i] * dv);
    }
  }
}

// ---------------- gather + BN + ReLU (16-lane group/node, MLP=8 — R11 shape) ----------------

__global__ __launch_bounds__(256) void k_gather8(const f16* __restrict__ HWS,
                                                 const int* __restrict__ rowpack,
                                                 const int* __restrict__ col,
                                                 const float* __restrict__ scsh,
                                                 float* __restrict__ outF,
                                                 f16* __restrict__ outH,
                                                 int last) {
  int tid = blockIdx.x * 256 + threadIdx.x;
  int wid = tid >> 4;
  int cs = tid & 15;
  if (wid >= N_NODES) return;
  int rp = rowpack[wid];
  int deg = rp & 0x3FFF;
  int off = rp >> 14;
  int pdeg = (deg + 3) & ~3;
  int beg = (wid >> BSHIFT) * CAP_C + off;
  const f16x8* h8 = (const f16x8*)HWS;

  f16x8 a0 = h8[(size_t)wid * 16 + cs];  // self row
  f16x8 a1 = {}, a2 = {}, a3 = {};
  int j = 0;
  for (; j + 8 <= pdeg; j += 8) {
    int4 c0 = *(const int4*)(col + beg + j);
    int4 c1 = *(const int4*)(col + beg + j + 4);
    f16x8 v0 = h8[(size_t)c0.x * 16 + cs];
    f16x8 v1 = h8[(size_t)c0.y * 16 + cs];
    f16x8 v2 = h8[(size_t)c0.z * 16 + cs];
    f16x8 v3 = h8[(size_t)c0.w * 16 + cs];
    f16x8 v4 = h8[(size_t)c1.x * 16 + cs];
    f16x8 v5 = h8[(size_t)c1.y * 16 + cs];
    f16x8 v6 = h8[(size_t)c1.z * 16 + cs];
    f16x8 v7 = h8[(size_t)c1.w * 16 + cs];
    a0 += v0; a1 += v1; a2 += v2; a3 += v3;
    a0 += v4; a1 += v5; a2 += v6; a3 += v7;
  }
  if (j < pdeg) {  // exactly one 4-batch
    int4 c0 = *(const int4*)(col + beg + j);
    f16x8 v0 = h8[(size_t)c0.x * 16 + cs];
    f16x8 v1 = h8[(size_t)c0.y * 16 + cs];
    f16x8 v2 = h8[(size_t)c0.z * 16 + cs];
    f16x8 v3 = h8[(size_t)c0.w * 16 + cs];
    a0 += v0; a1 += v1; a2 += v2; a3 += v3;
  }
  a0 += a1; a2 += a3; a0 += a2;

  float di = rsqrtf((float)(deg + 1));
  int c4 = cs * 2;
  const f32x4* scv = (const f32x4*)scsh;
  const f32x4* shv = (const f32x4*)(scsh + 128);
  float o[8];
  #pragma unroll
  for (int half = 0; half < 2; half++) {
    f32x4 sc = scv[c4 + half], sh = shv[c4 + half];
    #pragma unroll
    for (int i = 0; i < 4; i++) {
      float v = (float)a0[half * 4 + i] * di;
      o[half * 4 + i] = fmaxf(fmaf(v, sc[i], sh[i]), 0.f);
    }
  }
  if (last) {
    f32x4* of = (f32x4*)outF;
    f32x4 lo = {o[0], o[1], o[2], o[3]}, hi = {o[4], o[5], o[6], o[7]};
    of[(size_t)wid * 32 + c4] = lo;
    of[(size_t)wid * 32 + c4 + 1] = hi;
  } else {
    f16x8 oh = {(f16)o[0], (f16)o[1], (f16)o[2], (f16)o[3],
                (f16)o[4], (f16)o[5], (f16)o[6], (f16)o[7]};
    ((f16x8*)outH)[(size_t)wid * 16 + cs] = oh;
  }
}

// ---------------- launch ----------------

extern "C" void kernel_launch(void* const* d_in, const int* in_sizes, int n_in,
                              void* d_out, int out_size, void* d_ws, size_t ws_size,
                              hipStream_t stream) {
  const float* x = (const float*)d_in[0];
  const int* ei = (const int*)d_in[1];
  const int* srcv = ei;             // edge_index[0]
  const int* dstv = ei + N_EDGES;   // edge_index[1]
  const float* W     = (const float*)d_in[3];
  const float* b     = (const float*)d_in[4];
  const float* gamma = (const float*)d_in[5];
  const float* beta  = (const float*)d_in[6];
  const float* rmean = (const float*)d_in[7];
  const float* rvar  = (const float*)d_in[8];
  float* out = (float*)d_out;

  // workspace layout (bytes, 128-aligned)
  const size_t off_rowpack = 0;                        // N ints
  const size_t off_col     = 400128;                   // NB*CAP_C ints = 7,877,632
  const size_t off_scsh    = 400128 + 7877632;         // 3*256 floats
  const size_t off_wt      = off_scsh + 3072;          // 3*128*128 fp16 = 96 KB
  const size_t off_h16     = off_wt + 98304;           // N*256 B (stage aliases)
  const size_t off_hws     = off_h16 + 25600000;       // (N+1)*256 B (bcnt aliases)
  const size_t need = off_hws + 25600256;              // ~59.6 MB
  if (ws_size < need) return;

  char* ws = (char*)d_ws;
  int*   rowpack = (int*)(ws + off_rowpack);
  int*   col     = (int*)(ws + off_col);
  float* scsh    = (float*)(ws + off_scsh);
  f16*   wt      = (f16*)(ws + off_wt);
  f16*   h16     = (f16*)(ws + off_h16);
  f16*   hws     = (f16*)(ws + off_hws);
  int2*  stage   = (int2*)(ws + off_h16);   // 14.45 MB; dead before gather L0 writes h16
  int*   bcnt    = (int*)(ws + off_hws);    // 784 B; dead before gemm0 writes hws

  k_prep<<<193, 256, 0, stream>>>(W, b, gamma, beta, rmean, rvar, wt, scsh, hws, bcnt);
  k_binA<<<(N_EDGES + CHUNK - 1) / CHUNK, 256, 0, stream>>>(srcv, dstv, bcnt, stage);
  k_binB<<<NB, 512, 0, stream>>>(stage, bcnt, rowpack, col);

  k_gemm0<<<1563, 256, 0, stream>>>(x, wt, rowpack, hws);
  k_gather8<<<6250, 256, 0, stream>>>(hws, rowpack, col, scsh, out, h16, 0);
  k_gemm16<<<1563, 256, 0, stream>>>(h16, wt + DIM * DIM, rowpack, hws);
  k_gather8<<<6250, 256, 0, stream>>>(hws, rowpack, col, scsh + 256, out, h16, 0);
  k_gemm16<<<1563, 256, 0, stream>>>(h16, wt + 2 * DIM * DIM, rowpack, hws);
  k_gather8<<<6250, 256, 0, stream>>>(hws, rowpack, col, scsh + 512, out, h16, 1);
}